// Round 6
// baseline (731.573 us; speedup 1.0000x reference)
//
#include <hip/hip_runtime.h>
#include <stdint.h>

// ---------------------------------------------------------------------------
// GCN 5-layer, N=50000, E=600000.  out = ((Anorm @ h) @ W) + b per layer.
// Activations: f16 hi/lo (22-bit mantissa), packed (h,l) u32 per feature.
// Layers 1-4: ONE fused kernel per layer: phase A gathers+aggregates 32 dst
// rows into LDS (XOR-swizzled hi/lo f16 planes), phase B does the f16x3
// split-MFMA GEMM (AhBh+AhBl+AlBh) with B staged via global_load_lds.
// Packed activations ping-pong P0<->P1 (no read/write race).
// L5: narrow GEMM (256->64) then f32 aggregation + bias.
// ---------------------------------------------------------------------------

typedef _Float16 v8h __attribute__((ext_vector_type(8)));
typedef _Float16 v4h __attribute__((ext_vector_type(4)));
typedef _Float16 v2h __attribute__((ext_vector_type(2)));
typedef float v4f __attribute__((ext_vector_type(4)));

// ---------------- CSR build ----------------
__global__ void count_edges(const int* __restrict__ dst, int E, int* __restrict__ counts) {
    int i = blockIdx.x * blockDim.x + threadIdx.x;
    if (i < E) atomicAdd(&counts[dst[i]], 1);
}

__global__ void block_sums(const int* __restrict__ counts, int n, int* __restrict__ partial) {
    __shared__ int red[256];
    int t = threadIdx.x;
    int i = blockIdx.x * 256 + t;
    red[t] = (i < n) ? counts[i] : 0;
    __syncthreads();
    #pragma unroll
    for (int off = 128; off > 0; off >>= 1) {
        if (t < off) red[t] += red[t + off];
        __syncthreads();
    }
    if (t == 0) partial[blockIdx.x] = red[0];
}

__global__ void scan_partials(int* __restrict__ partial, int nb, int* __restrict__ row_ptr, int n) {
    __shared__ int s[256];
    int t = threadIdx.x;
    int v = (t < nb) ? partial[t] : 0;
    s[t] = v;
    __syncthreads();
    #pragma unroll
    for (int off = 1; off < 256; off <<= 1) {
        int u = (t >= off) ? s[t - off] : 0;
        __syncthreads();
        s[t] += u;
        __syncthreads();
    }
    if (t < nb) partial[t] = s[t] - v;
    if (t == 0) row_ptr[n] = s[255];
}

__global__ void scan_final(const int* __restrict__ counts, int n, const int* __restrict__ partial,
                           int* __restrict__ row_ptr, float* __restrict__ dinv,
                           int* __restrict__ fill) {
    __shared__ int s[256];
    int t = threadIdx.x;
    int i = blockIdx.x * 256 + t;
    int c = (i < n) ? counts[i] : 0;
    s[t] = c;
    __syncthreads();
    #pragma unroll
    for (int off = 1; off < 256; off <<= 1) {
        int u = (t >= off) ? s[t - off] : 0;
        __syncthreads();
        s[t] += u;
        __syncthreads();
    }
    if (i < n) {
        row_ptr[i] = partial[blockIdx.x] + s[t] - c;
        dinv[i] = rsqrtf((float)(c + 1));
        fill[i] = 0;
    }
}

__global__ void build_csr(const int* __restrict__ src, const int* __restrict__ dst, int E,
                          const int* __restrict__ row_ptr, int* __restrict__ fill,
                          int2* __restrict__ esw, const float* __restrict__ dinv) {
    int i = blockIdx.x * blockDim.x + threadIdx.x;
    if (i < E) {
        int d = dst[i];
        int s = src[i];
        int pos = row_ptr[d] + atomicAdd(&fill[d], 1);
        esw[pos] = make_int2(s, __float_as_int(dinv[s]));
    }
}

// ---------------- weight split+transpose (all 5 layers, one launch) ----------------
struct SplitArgs {
    const float* W[5];
    _Float16* Wh[5];
    _Float16* Wl[5];
    int lgFI[5];
    int FO[5];
    int off[6];
};

__global__ void split_all(SplitArgs a) {
    int i = blockIdx.x * 256 + threadIdx.x;
    #pragma unroll
    for (int l = 0; l < 5; ++l) {
        if (i >= a.off[l] && i < a.off[l + 1]) {
            int j = i - a.off[l];
            int FI = 1 << a.lgFI[l];
            int c = j >> a.lgFI[l];
            int k = j & (FI - 1);
            float v = a.W[l][(size_t)k * a.FO[l] + c];
            _Float16 h = (_Float16)v;
            a.Wh[l][j] = h;
            a.Wl[l][j] = (_Float16)(v - (float)h);
        }
    }
}

// ---------------- async global->LDS ----------------
__device__ __forceinline__ void gl_lds16(const _Float16* g, _Float16* l) {
    __builtin_amdgcn_global_load_lds(
        (const __attribute__((address_space(1))) uint32_t*)g,
        (__attribute__((address_space(3))) uint32_t*)l, 16, 0, 0);
}

// ---------------- fused layer: aggregate 32 rows -> LDS -> GEMM ----------------
// INMODE 0: in = f32 [n][128] (L1).  INMODE 1: in = packed u32 (h|l<<16) [n][256].
// OUTMODE 0: packed u32 out.         OUTMODE 1: hi/lo plane out (for L5 staging).
// Block: 256 threads (4 waves), 32 dst rows, full 256-col output.
template <int FI, int INMODE, int OUTMODE>
__global__ __launch_bounds__(256) void layer_fused(
    const void* __restrict__ in, const int* __restrict__ row_ptr,
    const int2* __restrict__ esw, const float* __restrict__ dinv,
    const _Float16* __restrict__ Wth, const _Float16* __restrict__ Wtl,  // [256][FI]
    const float* __restrict__ bias,
    uint32_t* __restrict__ Opk, _Float16* __restrict__ Oh, _Float16* __restrict__ Ol,
    int n) {
    constexpr int ALO = 32 * FI;          // f16 idx of lo A-plane
    constexpr int BH = 64 * FI;           // f16 idx of B hi staging (8192 f16)
    constexpr int BL = 64 * FI + 8192;    // f16 idx of B lo staging
    constexpr int NSTEP = FI / 32;
    __shared__ _Float16 lds[64 * FI + 16384];
    const int m0 = blockIdx.x * 32;
    const int t = threadIdx.x;
    const int w = t >> 6;
    const int lane = t & 63;

    // ---------------- phase A: aggregate 8 rows per wave into LDS ----------------
    for (int q = 0; q < 8; ++q) {
        const int r = w * 8 + q;
        const int grow = m0 + r;
        if constexpr (INMODE == 1) {
            float s0 = 0.f, s1 = 0.f, s2 = 0.f, s3 = 0.f;
            if (grow < n) {
                const _Float16* rb = (const _Float16*)in + (size_t)lane * 8;
                int e = __builtin_amdgcn_readfirstlane(row_ptr[grow]);
                const int end = __builtin_amdgcn_readfirstlane(row_ptr[grow + 1]);
                const float dd = dinv[grow];
                float a0, a1, a2, a3;
                {
                    v8h p = *(const v8h*)(rb + (size_t)grow * 512);
                    a0 = dd * ((float)p[0] + (float)p[1]);
                    a1 = dd * ((float)p[2] + (float)p[3]);
                    a2 = dd * ((float)p[4] + (float)p[5]);
                    a3 = dd * ((float)p[6] + (float)p[7]);
                }
#define GTH(qq) (*(const v8h*)(rb + (size_t)(qq).x * 512))
#define ACC(b, wv)                                   \
    a0 += (wv) * ((float)(b)[0] + (float)(b)[1]);    \
    a1 += (wv) * ((float)(b)[2] + (float)(b)[3]);    \
    a2 += (wv) * ((float)(b)[4] + (float)(b)[5]);    \
    a3 += (wv) * ((float)(b)[6] + (float)(b)[7]);
                for (; e + 8 <= end; e += 8) {
                    int2 q0 = esw[e + 0], q1 = esw[e + 1], q2 = esw[e + 2], q3 = esw[e + 3];
                    int2 q4 = esw[e + 4], q5 = esw[e + 5], q6 = esw[e + 6], q7 = esw[e + 7];
                    v8h b0 = GTH(q0), b1 = GTH(q1), b2 = GTH(q2), b3 = GTH(q3);
                    v8h b4 = GTH(q4), b5 = GTH(q5), b6 = GTH(q6), b7 = GTH(q7);
                    ACC(b0, __int_as_float(q0.y)) ACC(b1, __int_as_float(q1.y))
                    ACC(b2, __int_as_float(q2.y)) ACC(b3, __int_as_float(q3.y))
                    ACC(b4, __int_as_float(q4.y)) ACC(b5, __int_as_float(q5.y))
                    ACC(b6, __int_as_float(q6.y)) ACC(b7, __int_as_float(q7.y))
                }
                if (e + 4 <= end) {
                    int2 q0 = esw[e + 0], q1 = esw[e + 1], q2 = esw[e + 2], q3 = esw[e + 3];
                    v8h b0 = GTH(q0), b1 = GTH(q1), b2 = GTH(q2), b3 = GTH(q3);
                    ACC(b0, __int_as_float(q0.y)) ACC(b1, __int_as_float(q1.y))
                    ACC(b2, __int_as_float(q2.y)) ACC(b3, __int_as_float(q3.y))
                    e += 4;
                }
                if (e < end) {
                    const int em = end - 1;
                    int e1 = (e + 1 < end) ? e + 1 : em;
                    int e2 = (e + 2 < end) ? e + 2 : em;
                    int2 q0 = esw[e], q1 = esw[e1], q2 = esw[e2], q3 = esw[em];
                    float w0 = __int_as_float(q0.y);
                    float w1 = (e + 1 < end) ? __int_as_float(q1.y) : 0.f;
                    float w2 = (e + 2 < end) ? __int_as_float(q2.y) : 0.f;
                    float w3 = (e + 3 < end) ? __int_as_float(q3.y) : 0.f;
                    v8h b0 = GTH(q0), b1 = GTH(q1), b2 = GTH(q2), b3 = GTH(q3);
                    ACC(b0, w0) ACC(b1, w1) ACC(b2, w2) ACC(b3, w3)
                }
#undef GTH
#undef ACC
                s0 = dd * a0; s1 = dd * a1; s2 = dd * a2; s3 = dd * a3;
            }
            _Float16 h0 = (_Float16)s0, h1 = (_Float16)s1, h2 = (_Float16)s2, h3 = (_Float16)s3;
            const int idx = (r * 256 + lane * 4) ^ ((r & 7) << 3);
            *(v4h*)&lds[idx] = (v4h){h0, h1, h2, h3};
            *(v4h*)&lds[ALO + idx] = (v4h){(_Float16)(s0 - (float)h0), (_Float16)(s1 - (float)h1),
                                           (_Float16)(s2 - (float)h2), (_Float16)(s3 - (float)h3)};
        } else {
            float s0 = 0.f, s1 = 0.f;
            if (grow < n) {
                const float* rb = (const float*)in + (size_t)lane * 2;
                int e = __builtin_amdgcn_readfirstlane(row_ptr[grow]);
                const int end = __builtin_amdgcn_readfirstlane(row_ptr[grow + 1]);
                const float dd = dinv[grow];
                float a0, a1;
                {
                    float2 p = *(const float2*)(rb + (size_t)grow * 128);
                    a0 = dd * p.x;
                    a1 = dd * p.y;
                }
#define GTH(qq) (*(const float2*)(rb + (size_t)(qq).x * 128))
#define ACC(b, wv) a0 += (wv) * (b).x; a1 += (wv) * (b).y;
                for (; e + 8 <= end; e += 8) {
                    int2 q0 = esw[e + 0], q1 = esw[e + 1], q2 = esw[e + 2], q3 = esw[e + 3];
                    int2 q4 = esw[e + 4], q5 = esw[e + 5], q6 = esw[e + 6], q7 = esw[e + 7];
                    float2 b0 = GTH(q0), b1 = GTH(q1), b2 = GTH(q2), b3 = GTH(q3);
                    float2 b4 = GTH(q4), b5 = GTH(q5), b6 = GTH(q6), b7 = GTH(q7);
                    ACC(b0, __int_as_float(q0.y)) ACC(b1, __int_as_float(q1.y))
                    ACC(b2, __int_as_float(q2.y)) ACC(b3, __int_as_float(q3.y))
                    ACC(b4, __int_as_float(q4.y)) ACC(b5, __int_as_float(q5.y))
                    ACC(b6, __int_as_float(q6.y)) ACC(b7, __int_as_float(q7.y))
                }
                if (e + 4 <= end) {
                    int2 q0 = esw[e + 0], q1 = esw[e + 1], q2 = esw[e + 2], q3 = esw[e + 3];
                    float2 b0 = GTH(q0), b1 = GTH(q1), b2 = GTH(q2), b3 = GTH(q3);
                    ACC(b0, __int_as_float(q0.y)) ACC(b1, __int_as_float(q1.y))
                    ACC(b2, __int_as_float(q2.y)) ACC(b3, __int_as_float(q3.y))
                    e += 4;
                }
                if (e < end) {
                    const int em = end - 1;
                    int e1 = (e + 1 < end) ? e + 1 : em;
                    int e2 = (e + 2 < end) ? e + 2 : em;
                    int2 q0 = esw[e], q1 = esw[e1], q2 = esw[e2], q3 = esw[em];
                    float w0 = __int_as_float(q0.y);
                    float w1 = (e + 1 < end) ? __int_as_float(q1.y) : 0.f;
                    float w2 = (e + 2 < end) ? __int_as_float(q2.y) : 0.f;
                    float w3 = (e + 3 < end) ? __int_as_float(q3.y) : 0.f;
                    float2 b0 = GTH(q0), b1 = GTH(q1), b2 = GTH(q2), b3 = GTH(q3);
                    ACC(b0, w0) ACC(b1, w1) ACC(b2, w2) ACC(b3, w3)
                }
#undef GTH
#undef ACC
                s0 = dd * a0; s1 = dd * a1;
            }
            _Float16 h0 = (_Float16)s0, h1 = (_Float16)s1;
            const int idx = (r * 128 + lane * 2) ^ ((r & 7) << 3);
            *(v2h*)&lds[idx] = (v2h){h0, h1};
            *(v2h*)&lds[ALO + idx] = (v2h){(_Float16)(s0 - (float)h0), (_Float16)(s1 - (float)h1)};
        }
    }
    __syncthreads();

    // ---------------- phase B: GEMM on the LDS A-planes ----------------
    // B staging offsets (wave w stages col-subtiles w*4+q)
    size_t boff[4];
    #pragma unroll
    for (int q = 0; q < 4; ++q)
        boff[q] = (size_t)((w * 4 + q) * 16 + (lane & 15)) * FI + ((lane >> 4) * 8);

    v4f acc[2][4];
    #pragma unroll
    for (int i = 0; i < 2; ++i)
        #pragma unroll
        for (int j = 0; j < 4; ++j) acc[i][j] = (v4f){0.f, 0.f, 0.f, 0.f};

    for (int s = 0; s < NSTEP; ++s) {
        const int ko = s * 32;
        #pragma unroll
        for (int q = 0; q < 4; ++q) {
            gl_lds16(Wth + boff[q] + ko, &lds[BH + (w * 4 + q) * 512]);
            gl_lds16(Wtl + boff[q] + ko, &lds[BL + (w * 4 + q) * 512]);
        }
        __syncthreads();
        v8h ahf[2], alf[2], bhf[4], blf[4];
        #pragma unroll
        for (int i = 0; i < 2; ++i) {
            const int ri = i * 16 + (lane & 15);
            const int aidx = (ri * FI + ko + ((lane >> 4) << 3)) ^ ((lane & 7) << 3);
            ahf[i] = *(const v8h*)&lds[aidx];
            alf[i] = *(const v8h*)&lds[ALO + aidx];
        }
        #pragma unroll
        for (int j = 0; j < 4; ++j) {
            bhf[j] = *(const v8h*)&lds[BH + (w * 4 + j) * 512 + lane * 8];
            blf[j] = *(const v8h*)&lds[BL + (w * 4 + j) * 512 + lane * 8];
        }
        #pragma unroll
        for (int i = 0; i < 2; ++i)
            #pragma unroll
            for (int j = 0; j < 4; ++j) {
                acc[i][j] = __builtin_amdgcn_mfma_f32_16x16x32_f16(ahf[i], bhf[j], acc[i][j], 0, 0, 0);
                acc[i][j] = __builtin_amdgcn_mfma_f32_16x16x32_f16(ahf[i], blf[j], acc[i][j], 0, 0, 0);
                acc[i][j] = __builtin_amdgcn_mfma_f32_16x16x32_f16(alf[i], bhf[j], acc[i][j], 0, 0, 0);
            }
        __syncthreads();
    }

    const int rl = (lane >> 4) * 4;
    const int cl = lane & 15;
    #pragma unroll
    for (int j = 0; j < 4; ++j) {
        const int gcol = w * 64 + j * 16 + cl;
        const float bv = bias[gcol];
        #pragma unroll
        for (int i = 0; i < 2; ++i) {
            const int growb = m0 + i * 16 + rl;
            #pragma unroll
            for (int r = 0; r < 4; ++r) {
                if (growb + r < n) {
                    float v = fmaxf(acc[i][j][r] + bv, 0.f);
                    _Float16 h = (_Float16)v;
                    _Float16 l = (_Float16)(v - (float)h);
                    if (OUTMODE == 0) {
                        uint32_t u = (uint32_t)__builtin_bit_cast(uint16_t, h) |
                                     ((uint32_t)__builtin_bit_cast(uint16_t, l) << 16);
                        Opk[(size_t)(growb + r) * 256 + gcol] = u;
                    } else {
                        Oh[(size_t)(growb + r) * 256 + gcol] = h;
                        Ol[(size_t)(growb + r) * 256 + gcol] = l;
                    }
                }
            }
        }
    }
}

// ---------------- L5 narrow GEMM: out[n x 64] f32 = A @ Wt^T ----------------
__global__ __launch_bounds__(256) void gemm_narrow(
    const _Float16* __restrict__ Ah, const _Float16* __restrict__ Al,
    const _Float16* __restrict__ Wth, const _Float16* __restrict__ Wtl,  // [64][256]
    float* __restrict__ Of, int n) {
    constexpr int FI = 256, FO = 64;
    __shared__ _Float16 lds[12288];
    const int m0 = blockIdx.x * 128;
    const int t = threadIdx.x;
    const int w = t >> 6;
    const int lane = t & 63;

    const int G0 = w * 128 + lane;
    const int G1 = G0 + 64;
    const int arow0 = (G0 >> 6) * 16 + (G0 & 15), akc0 = ((G0 >> 4) & 3) * 8;
    const int arow1 = (G1 >> 6) * 16 + (G1 & 15), akc1 = ((G1 >> 4) & 3) * 8;
    const _Float16* sAh0 = Ah + (size_t)(m0 + arow0) * FI + akc0;
    const _Float16* sAh1 = Ah + (size_t)(m0 + arow1) * FI + akc1;
    const _Float16* sAl0 = Al + (size_t)(m0 + arow0) * FI + akc0;
    const _Float16* sAl1 = Al + (size_t)(m0 + arow1) * FI + akc1;
    const int bcol = w * 16 + (lane & 15), bkc = (lane >> 4) * 8;
    const _Float16* sBh = Wth + (size_t)bcol * FI + bkc;
    const _Float16* sBl = Wtl + (size_t)bcol * FI + bkc;

    _Float16* dAh0 = &lds[w * 1024];
    _Float16* dAh1 = &lds[w * 1024 + 512];
    _Float16* dAl0 = &lds[4096 + w * 1024];
    _Float16* dAl1 = &lds[4096 + w * 1024 + 512];
    _Float16* dBh = &lds[8192 + w * 512];
    _Float16* dBl = &lds[10240 + w * 512];

    const int wm = w >> 1, wn = w & 1;
    v4f acc[4][2];
    #pragma unroll
    for (int i = 0; i < 4; ++i)
        #pragma unroll
        for (int j = 0; j < 2; ++j) acc[i][j] = (v4f){0.f, 0.f, 0.f, 0.f};

    for (int s = 0; s < 8; ++s) {
        const int ko = s * 32;
        gl_lds16(sAh0 + ko, dAh0);
        gl_lds16(sAh1 + ko, dAh1);
        gl_lds16(sAl0 + ko, dAl0);
        gl_lds16(sAl1 + ko, dAl1);
        gl_lds16(sBh + ko, dBh);
        gl_lds16(sBl + ko, dBl);
        __syncthreads();
        v8h ah[4], al[4], bh[2], bl[2];
        #pragma unroll
        for (int i = 0; i < 4; ++i) {
            ah[i] = *(const v8h*)&lds[(wm * 4 + i) * 512 + lane * 8];
            al[i] = *(const v8h*)&lds[4096 + (wm * 4 + i) * 512 + lane * 8];
        }
        #pragma unroll
        for (int j = 0; j < 2; ++j) {
            bh[j] = *(const v8h*)&lds[8192 + (wn * 2 + j) * 512 + lane * 8];
            bl[j] = *(const v8h*)&lds[10240 + (wn * 2 + j) * 512 + lane * 8];
        }
        #pragma unroll
        for (int i = 0; i < 4; ++i)
            #pragma unroll
            for (int j = 0; j < 2; ++j) {
                acc[i][j] = __builtin_amdgcn_mfma_f32_16x16x32_f16(ah[i], bh[j], acc[i][j], 0, 0, 0);
                acc[i][j] = __builtin_amdgcn_mfma_f32_16x16x32_f16(ah[i], bl[j], acc[i][j], 0, 0, 0);
                acc[i][j] = __builtin_amdgcn_mfma_f32_16x16x32_f16(al[i], bh[j], acc[i][j], 0, 0, 0);
            }
        __syncthreads();
    }

    const int rl = (lane >> 4) * 4;
    const int cl = lane & 15;
    #pragma unroll
    for (int j = 0; j < 2; ++j) {
        const int gcol = wn * 32 + j * 16 + cl;
        #pragma unroll
        for (int i = 0; i < 4; ++i) {
            const int grow = m0 + wm * 64 + i * 16 + rl;
            #pragma unroll
            for (int r = 0; r < 4; ++r)
                if (grow + r < n) Of[(size_t)(grow + r) * FO + gcol] = acc[i][j][r];
        }
    }
}

// ---------------- L5 aggregation: f32 64 feats + bias ----------------
__global__ __launch_bounds__(256) void agg_f32_64(
    const float* __restrict__ in, const int* __restrict__ row_ptr,
    const int2* __restrict__ esw, const float* __restrict__ dinv,
    const float* __restrict__ bias, float* __restrict__ outF, int n) {
    int wid = (blockIdx.x * blockDim.x + threadIdx.x) >> 6;
    if (wid >= n) return;
    const int lane = threadIdx.x & 63;
    int e = __builtin_amdgcn_readfirstlane(row_ptr[wid]);
    const int end = __builtin_amdgcn_readfirstlane(row_ptr[wid + 1]);
    const float dd = dinv[wid];
    const float* rb = in + lane;
    float a0 = dd * rb[(size_t)wid * 64];
#define GTH(q) (rb[(size_t)(q).x * 64])
    for (; e + 8 <= end; e += 8) {
        int2 q0 = esw[e + 0], q1 = esw[e + 1], q2 = esw[e + 2], q3 = esw[e + 3];
        int2 q4 = esw[e + 4], q5 = esw[e + 5], q6 = esw[e + 6], q7 = esw[e + 7];
        float b0 = GTH(q0), b1 = GTH(q1), b2 = GTH(q2), b3 = GTH(q3);
        float b4 = GTH(q4), b5 = GTH(q5), b6 = GTH(q6), b7 = GTH(q7);
        a0 += __int_as_float(q0.y) * b0 + __int_as_float(q1.y) * b1;
        a0 += __int_as_float(q2.y) * b2 + __int_as_float(q3.y) * b3;
        a0 += __int_as_float(q4.y) * b4 + __int_as_float(q5.y) * b5;
        a0 += __int_as_float(q6.y) * b6 + __int_as_float(q7.y) * b7;
    }
    if (e + 4 <= end) {
        int2 q0 = esw[e + 0], q1 = esw[e + 1], q2 = esw[e + 2], q3 = esw[e + 3];
        float b0 = GTH(q0), b1 = GTH(q1), b2 = GTH(q2), b3 = GTH(q3);
        a0 += __int_as_float(q0.y) * b0 + __int_as_float(q1.y) * b1;
        a0 += __int_as_float(q2.y) * b2 + __int_as_float(q3.y) * b3;
        e += 4;
    }
    if (e < end) {
        const int em = end - 1;
        int e1 = (e + 1 < end) ? e + 1 : em;
        int e2 = (e + 2 < end) ? e + 2 : em;
        int2 q0 = esw[e], q1 = esw[e1], q2 = esw[e2], q3 = esw[em];
        float w0 = __int_as_float(q0.y);
        float w1 = (e + 1 < end) ? __int_as_float(q1.y) : 0.f;
        float w2 = (e + 2 < end) ? __int_as_float(q2.y) : 0.f;
        float w3 = (e + 3 < end) ? __int_as_float(q3.y) : 0.f;
        float b0 = GTH(q0), b1 = GTH(q1), b2 = GTH(q2), b3 = GTH(q3);
        a0 += w0 * b0 + w1 * b1 + w2 * b2 + w3 * b3;
    }
#undef GTH
    outF[(size_t)wid * 64 + lane] = dd * a0 + bias[lane];
}

// ---------------- launcher ----------------
extern "C" void kernel_launch(void* const* d_in, const int* in_sizes, int n_in,
                              void* d_out, int out_size, void* d_ws, size_t ws_size,
                              hipStream_t stream) {
    const float* x = (const float*)d_in[0];
    const int* ei = (const int*)d_in[1];
    const int E = in_sizes[1] / 2;
    const int n = in_sizes[0] / 128;
    const int* esrc = ei;
    const int* edst = ei + E;
    const float* b[5] = {(const float*)d_in[3], (const float*)d_in[5], (const float*)d_in[7],
                         (const float*)d_in[9], (const float*)d_in[11]};
    float* out = (float*)d_out;
    const int NPAD = ((n + 127) / 128) * 128;

    char* ws = (char*)d_ws;
    auto carve = [&](size_t bytes) {
        char* p = ws;
        ws += (bytes + 255) & ~(size_t)255;
        return p;
    };
    int* counts = (int*)carve((size_t)n * 4);
    int* row_ptr = (int*)carve((size_t)(n + 1) * 4);
    int* fill = (int*)carve((size_t)n * 4);
    float* dinv = (float*)carve((size_t)n * 4);
    int* partial = (int*)carve(1024);
    int2* esw = (int2*)carve((size_t)E * 8);
    const int FIs[5] = {128, 256, 256, 256, 256};
    const int FOs[5] = {256, 256, 256, 256, 64};
    _Float16 *Wh[5], *Wl[5];
    for (int l = 0; l < 5; ++l) {
        Wh[l] = (_Float16*)carve((size_t)FIs[l] * FOs[l] * 2);
        Wl[l] = (_Float16*)carve((size_t)FIs[l] * FOs[l] * 2);
    }
    uint32_t* P0 = (uint32_t*)carve((size_t)NPAD * 256 * 4);  // packed ping
    uint32_t* P1 = (uint32_t*)carve((size_t)NPAD * 256 * 4);  // packed pong
    _Float16* Bh2 = (_Float16*)P1;                            // L4 planes (in P1)
    _Float16* Bl2 = (_Float16*)P1 + (size_t)NPAD * 256;
    float* scratch = (float*)P0;                              // L5 gemm f32 out

    hipMemsetAsync(counts, 0, (size_t)n * 4, stream);
    count_edges<<<(E + 255) / 256, 256, 0, stream>>>(edst, E, counts);
    const int nsb = (n + 255) / 256;
    block_sums<<<nsb, 256, 0, stream>>>(counts, n, partial);
    scan_partials<<<1, 256, 0, stream>>>(partial, nsb, row_ptr, n);
    scan_final<<<nsb, 256, 0, stream>>>(counts, n, partial, row_ptr, dinv, fill);
    build_csr<<<(E + 255) / 256, 256, 0, stream>>>(esrc, edst, E, row_ptr, fill, esw, dinv);

    SplitArgs sa;
    int off = 0;
    for (int l = 0; l < 5; ++l) {
        sa.W[l] = (const float*)d_in[2 + 2 * l];
        sa.Wh[l] = Wh[l];
        sa.Wl[l] = Wl[l];
        sa.lgFI[l] = (FIs[l] == 128) ? 7 : 8;
        sa.FO[l] = FOs[l];
        sa.off[l] = off;
        off += FIs[l] * FOs[l];
    }
    sa.off[5] = off;
    split_all<<<(off + 255) / 256, 256, 0, stream>>>(sa);

    const int gf = NPAD / 32;  // fused-layer grid

    // L1: gather x (f32) -> GEMM 128->256 -> P0 packed
    layer_fused<128, 0, 0><<<gf, 256, 0, stream>>>(x, row_ptr, esw, dinv, Wh[0], Wl[0], b[0],
                                                   P0, nullptr, nullptr, n);
    // L2: P0 -> P1 ; L3: P1 -> P0
    layer_fused<256, 1, 0><<<gf, 256, 0, stream>>>(P0, row_ptr, esw, dinv, Wh[1], Wl[1], b[1],
                                                   P1, nullptr, nullptr, n);
    layer_fused<256, 1, 0><<<gf, 256, 0, stream>>>(P1, row_ptr, esw, dinv, Wh[2], Wl[2], b[2],
                                                   P0, nullptr, nullptr, n);
    // L4: P0 -> hi/lo planes (in P1)
    layer_fused<256, 1, 1><<<gf, 256, 0, stream>>>(P0, row_ptr, esw, dinv, Wh[3], Wl[3], b[3],
                                                   nullptr, Bh2, Bl2, n);
    // L5: narrow GEMM planes -> f32 scratch (P0); aggregate + bias -> out
    gemm_narrow<<<NPAD / 128, 256, 0, stream>>>(Bh2, Bl2, Wh[4], Wl[4], scratch, n);
    agg_f32_64<<<(n + 3) / 4, 256, 0, stream>>>(scratch, row_ptr, esw, dinv, b[4], out, n);
}